// Round 1
// baseline (101.352 us; speedup 1.0000x reference)
//
#include <hip/hip_runtime.h>
#include <cfloat>

// TripletSemiHardLoss — B=512, D=128, scalar f32 output.
// Kernel 1: one block per anchor j. Computes pdist row in LDS, fallback
//           hardest-negative, then per-positive semi-hard negative mining.
// Kernel 2: deterministic fixed-order tree reduction of 512 per-anchor
//           partials -> loss scalar. No float atomics (determinism).

constexpr int   BN       = 512;
constexpr int   DD       = 128;
constexpr float MARGIN_F = 0.1f;

__device__ inline float waveMin(float v) {
#pragma unroll
    for (int o = 32; o; o >>= 1) v = fminf(v, __shfl_down(v, o, 64));
    return v;
}
__device__ inline float waveMax(float v) {
#pragma unroll
    for (int o = 32; o; o >>= 1) v = fmaxf(v, __shfl_down(v, o, 64));
    return v;
}

__global__ __launch_bounds__(256) void triplet_anchor(
    const float* __restrict__ emb, const int* __restrict__ labels,
    float* __restrict__ loss_part, int* __restrict__ cnt_part)
{
    __shared__ float ej[DD];
    __shared__ float dist[BN];
    __shared__ int   lab[BN];
    __shared__ float sred[4];

    const int j = blockIdx.x;
    const int t = threadIdx.x;

    lab[t]       = labels[t];
    lab[t + 256] = labels[t + 256];
    if (t < DD) ej[t] = emb[(size_t)j * DD + t];
    __syncthreads();

    const int labj = lab[j];

    // --- pdist row j into LDS; fold local max over negatives (fallback) ---
    float locmax = 0.0f;   // row_min == 0 (diag) => reference masked-max init is 0
#pragma unroll
    for (int kk = 0; kk < 2; ++kk) {
        const int k = t + kk * 256;
        const float4* ek  = reinterpret_cast<const float4*>(emb + (size_t)k * DD);
        const float4* eja = reinterpret_cast<const float4*>(ej);
        float dot = 0.f, sqk = 0.f, sqj = 0.f;
#pragma unroll
        for (int q = 0; q < DD / 4; ++q) {
            float4 a = eja[q];
            float4 b = ek[q];
            dot += a.x * b.x + a.y * b.y + a.z * b.z + a.w * b.w;
            sqk += b.x * b.x + b.y * b.y + b.z * b.z + b.w * b.w;
            sqj += a.x * a.x + a.y * a.y + a.z * a.z + a.w * a.w;
        }
        float d = fmaxf(sqj + sqk - 2.f * dot, 0.f);
        if (k == j) d = 0.f;               // zero diagonal (exact)
        dist[k] = d;
        if (lab[k] != labj) locmax = fmaxf(locmax, d);
    }
    __syncthreads();

    // --- block max -> negatives_inside (hardest negative for anchor j) ---
    float wm = waveMax(locmax);
    if ((t & 63) == 0) sred[t >> 6] = wm;
    __syncthreads();
    const float neg_inside =
        fmaxf(fmaxf(sred[0], sred[1]), fmaxf(sred[2], sred[3]));

    // --- per-positive semi-hard negative mining ---
    float lsum = 0.f;
    int   lcnt = 0;
    for (int i = 0; i < BN; ++i) {
        if (i == j || lab[i] != labj) continue;   // uniform branch (LDS labels)
        const float dpos = dist[i];
        float mn = FLT_MAX;
#pragma unroll
        for (int kk = 0; kk < 2; ++kk) {
            const int   k  = t + kk * 256;
            const float dk = dist[k];
            if (lab[k] != labj && dk > dpos) mn = fminf(mn, dk);
        }
        mn = waveMin(mn);
        __syncthreads();                    // protect sred reads of prev iter
        if ((t & 63) == 0) sred[t >> 6] = mn;
        __syncthreads();
        const float m = fminf(fminf(sred[0], sred[1]), fminf(sred[2], sred[3]));
        const float shn = (m < FLT_MAX) ? m : neg_inside;
        lsum += fmaxf(MARGIN_F + dpos - shn, 0.f);
        ++lcnt;
    }
    if (t == 0) { loss_part[j] = lsum; cnt_part[j] = lcnt; }
}

__global__ __launch_bounds__(256) void triplet_finalize(
    const float* __restrict__ loss_part, const int* __restrict__ cnt_part,
    float* __restrict__ out)
{
    __shared__ float s[256];
    __shared__ int   c[256];
    const int t = threadIdx.x;
    s[t] = loss_part[t] + loss_part[t + 256];
    c[t] = cnt_part[t] + cnt_part[t + 256];
    __syncthreads();
    for (int o = 128; o; o >>= 1) {
        if (t < o) { s[t] += s[t + o]; c[t] += c[t + o]; }
        __syncthreads();
    }
    if (t == 0) out[0] = s[0] / (float)c[0];
}

extern "C" void kernel_launch(void* const* d_in, const int* in_sizes, int n_in,
                              void* d_out, int out_size, void* d_ws, size_t ws_size,
                              hipStream_t stream)
{
    const float* emb    = (const float*)d_in[0];
    const int*   labels = (const int*)d_in[1];
    float*       out    = (float*)d_out;
    float* loss_part = (float*)d_ws;
    int*   cnt_part  = (int*)((char*)d_ws + BN * sizeof(float));

    triplet_anchor<<<BN, 256, 0, stream>>>(emb, labels, loss_part, cnt_part);
    triplet_finalize<<<1, 256, 0, stream>>>(loss_part, cnt_part, out);
}

// Round 2
// 28.154 us; speedup vs baseline: 3.5999x; 3.5999x over previous
//
#include <hip/hip_runtime.h>
#include <cfloat>

// TripletSemiHardLoss — B=512, D=128, scalar f32 output.
// R2: latency fix. Per anchor j (one 256-thread block):
//   1) pdist row into LDS (float4 dots)
//   2) positives compacted via ballot+prefix (deterministic order)
//   3) each lane keeps 8 negative-dist candidates in REGISTERS
//   4) 4 waves mine positives in parallel: 8 reg compares + waveMin,
//      no LDS / no barriers in the inner loop.
// Kernel 2: fixed-order tree reduction (deterministic, no float atomics).

constexpr int   BN       = 512;
constexpr int   DD       = 128;
constexpr float MARGIN_F = 0.1f;

__device__ inline float waveMin(float v) {
#pragma unroll
    for (int o = 32; o; o >>= 1) v = fminf(v, __shfl_down(v, o, 64));
    return v;
}
__device__ inline float waveMax(float v) {
#pragma unroll
    for (int o = 32; o; o >>= 1) v = fmaxf(v, __shfl_down(v, o, 64));
    return v;
}

__global__ __launch_bounds__(256) void triplet_anchor(
    const float* __restrict__ emb, const int* __restrict__ labels,
    float* __restrict__ loss_part, int* __restrict__ cnt_part)
{
    __shared__ float ej[DD];
    __shared__ float dist[BN];
    __shared__ int   lab[BN];
    __shared__ int   cnt8[8];
    __shared__ short poslist[BN];
    __shared__ float wsum4[4];

    const int j    = blockIdx.x;
    const int t    = threadIdx.x;
    const int w    = t >> 6;
    const int lane = t & 63;

    lab[t]       = labels[t];
    lab[t + 256] = labels[t + 256];
    if (t < DD) ej[t] = emb[(size_t)j * DD + t];
    __syncthreads();

    const int labj = lab[j];

    // --- pdist row j into LDS ---
#pragma unroll
    for (int kk = 0; kk < 2; ++kk) {
        const int k = t + kk * 256;
        const float4* ek  = reinterpret_cast<const float4*>(emb + (size_t)k * DD);
        const float4* eja = reinterpret_cast<const float4*>(ej);
        float dot = 0.f, sqk = 0.f, sqj = 0.f;
#pragma unroll
        for (int q = 0; q < DD / 4; ++q) {
            float4 a = eja[q];
            float4 b = ek[q];
            dot += a.x * b.x + a.y * b.y + a.z * b.z + a.w * b.w;
            sqk += b.x * b.x + b.y * b.y + b.z * b.z + b.w * b.w;
            sqj += a.x * a.x + a.y * a.y + a.z * a.z + a.w * a.w;
        }
        float d = fmaxf(sqj + sqk - 2.f * dot, 0.f);
        if (k == j) d = 0.f;               // zero diagonal (exact)
        dist[k] = d;
    }

    // --- compact positives (deterministic ballot+prefix) ---
    const bool p0 = (lab[t] == labj)       && (t != j);
    const bool p1 = (lab[t + 256] == labj) && (t + 256 != j);
    const unsigned long long b0 = __ballot(p0);
    const unsigned long long b1 = __ballot(p1);
    if (lane == 0) { cnt8[w] = __popcll(b0); cnt8[4 + w] = __popcll(b1); }
    __syncthreads();   // dist[] + cnt8[] visible

    const int c0 = cnt8[0], c1 = cnt8[1], c2 = cnt8[2], c3 = cnt8[3];
    const int c4 = cnt8[4], c5 = cnt8[5], c6 = cnt8[6], c7 = cnt8[7];
    const int npos = c0 + c1 + c2 + c3 + c4 + c5 + c6 + c7;
    const unsigned long long ltm = (1ull << lane) - 1ull;
    if (p0) {
        int off = __popcll(b0 & ltm);
        for (int x = 0; x < w; ++x) off += cnt8[x];
        poslist[off] = (short)t;
    }
    if (p1) {
        int off = c0 + c1 + c2 + c3 + __popcll(b1 & ltm);
        for (int x = 0; x < w; ++x) off += cnt8[4 + x];
        poslist[off] = (short)(t + 256);
    }

    // --- hoist this lane's 8 candidates into registers ---
    const float4* dv = reinterpret_cast<const float4*>(&dist[lane * 8]);
    const float4  dA = dv[0], dB = dv[1];
    const int4*   lv = reinterpret_cast<const int4*>(&lab[lane * 8]);
    const int4    lA = lv[0], lB = lv[1];
    const float ddv[8] = {dA.x, dA.y, dA.z, dA.w, dB.x, dB.y, dB.z, dB.w};
    const int   llv[8] = {lA.x, lA.y, lA.z, lA.w, lB.x, lB.y, lB.z, lB.w};
    float dn[8];
    float nmax = 0.f;
#pragma unroll
    for (int q = 0; q < 8; ++q) {
        const bool neg = (llv[q] != labj);
        dn[q] = neg ? ddv[q] : FLT_MAX;
        nmax  = neg ? fmaxf(nmax, ddv[q]) : nmax;
    }
    const float neg_inside = waveMax(nmax);   // valid at lane 0 only

    __syncthreads();   // poslist[] visible

    // --- mine positives: wave w takes entries w, w+4, ... ---
    float wsum = 0.f;
    for (int e = w; e < npos; e += 4) {
        const int   i    = poslist[e];
        const float dpos = dist[i];            // LDS broadcast
        float mn = FLT_MAX;
#pragma unroll
        for (int q = 0; q < 8; ++q)
            mn = fminf(mn, (dn[q] > dpos) ? dn[q] : FLT_MAX);
        mn = waveMin(mn);                      // valid at lane 0
        if (lane == 0) {
            const float shn = (mn < FLT_MAX) ? mn : neg_inside;
            wsum += fmaxf(MARGIN_F + dpos - shn, 0.f);
        }
    }
    if (lane == 0) wsum4[w] = wsum;
    __syncthreads();
    if (t == 0) {
        loss_part[j] = (wsum4[0] + wsum4[1]) + (wsum4[2] + wsum4[3]);
        cnt_part[j]  = npos;
    }
}

__global__ __launch_bounds__(256) void triplet_finalize(
    const float* __restrict__ loss_part, const int* __restrict__ cnt_part,
    float* __restrict__ out)
{
    __shared__ float s[256];
    __shared__ int   c[256];
    const int t = threadIdx.x;
    s[t] = loss_part[t] + loss_part[t + 256];
    c[t] = cnt_part[t] + cnt_part[t + 256];
    __syncthreads();
    for (int o = 128; o; o >>= 1) {
        if (t < o) { s[t] += s[t + o]; c[t] += c[t + o]; }
        __syncthreads();
    }
    if (t == 0) out[0] = s[0] / (float)c[0];
}

extern "C" void kernel_launch(void* const* d_in, const int* in_sizes, int n_in,
                              void* d_out, int out_size, void* d_ws, size_t ws_size,
                              hipStream_t stream)
{
    const float* emb    = (const float*)d_in[0];
    const int*   labels = (const int*)d_in[1];
    float*       out    = (float*)d_out;
    float* loss_part = (float*)d_ws;
    int*   cnt_part  = (int*)((char*)d_ws + BN * sizeof(float));

    triplet_anchor<<<BN, 256, 0, stream>>>(emb, labels, loss_part, cnt_part);
    triplet_finalize<<<1, 256, 0, stream>>>(loss_part, cnt_part, out);
}